// Round 16
// baseline (607.392 us; speedup 1.0000x reference)
//
#include <hip/hip_runtime.h>
#include <cstdint>

typedef unsigned short u16;
typedef unsigned int   u32;

typedef __attribute__((ext_vector_type(8))) short bf16x8;
typedef __attribute__((ext_vector_type(4))) float f32x4;

#define DEV __device__ __forceinline__

static constexpr int HP = 66, WP = 66;   // padded spatial

DEV u16 f2bf(float f) {
  u32 u = __float_as_uint(f);
  u32 r = (u + 0x7fffu + ((u >> 16) & 1u)) >> 16;
  return (u16)r;
}
DEV float bf2f(u16 v) { return __uint_as_float((u32)v << 16); }

DEV void gload_lds16(const void* g, void* s) {
  __builtin_amdgcn_global_load_lds(
      (const __attribute__((address_space(1))) void*)g,
      (__attribute__((address_space(3))) void*)s, 16, 0, 0);
}

// ---- prep mega-kernel, segments by blockIdx.x ----
__global__ __launch_bounds__(256) void prep_kernel(const float* __restrict__ x,
                                                   const float* __restrict__ temb,
                                                   const float* __restrict__ temb_w,
                                                   const float* __restrict__ temb_b,
                                                   const float* __restrict__ conv1_b,
                                                   const float* __restrict__ style,
                                                   const float* __restrict__ style_w,
                                                   const float* __restrict__ style_b,
                                                   const float* __restrict__ conv1_w,
                                                   const float* __restrict__ mod_w,
                                                   float2* __restrict__ st1,
                                                   float* __restrict__ tb2,
                                                   float* __restrict__ mvec,
                                                   u16* __restrict__ w1T,
                                                   u16* __restrict__ wmT,
                                                   float* __restrict__ SS_T,
                                                   u16* __restrict__ act1p,
                                                   u16* __restrict__ act2p,
                                                   float* __restrict__ s2sum) {
  __shared__ float sh[512];
  int blk = blockIdx.x, t = threadIdx.x;
  if (blk < 1024) {
    const float4* p = (const float4*)(x + (size_t)blk * 16384);
    float s = 0.f, s2 = 0.f;
    for (int i = t; i < 4096; i += 256) {
      float4 v = p[i];
      s  += v.x + v.y + v.z + v.w;
      s2 += v.x*v.x + v.y*v.y + v.z*v.z + v.w*v.w;
    }
    for (int d = 32; d; d >>= 1) { s += __shfl_down(s, d); s2 += __shfl_down(s2, d); }
    if ((t & 63) == 0) { sh[t >> 6] = s; sh[4 + (t >> 6)] = s2; }
    __syncthreads();
    if (t == 0) {
      s  = sh[0] + sh[1] + sh[2] + sh[3];
      s2 = sh[4] + sh[5] + sh[6] + sh[7];
      float mean = s / 16384.f;
      float var  = s2 / 16384.f - mean * mean;
      st1[blk] = make_float2(mean, rsqrtf(var + 1e-5f));
    }
  } else if (blk < 1088) {
    int b2 = blk - 1024;
    if (b2 < 32) {
      int b = b2;
      for (int k = t; k < 512; k += 256) {
        float v = temb[b * 512 + k];
        sh[k] = v / (1.f + __expf(-v));
      }
      __syncthreads();
      const float4* wr = (const float4*)(temb_w + t * 512);
      float acc = 0.f;
      for (int k = 0; k < 128; ++k) {
        float4 w4 = wr[k];
        acc += w4.x * sh[k*4] + w4.y * sh[k*4+1] + w4.z * sh[k*4+2] + w4.w * sh[k*4+3];
      }
      tb2[b * 256 + t] = acc + temb_b[t] + conv1_b[t];
    } else {
      int b = b2 - 32;
      for (int k = t; k < 512; k += 256) sh[k] = style[b * 512 + k];
      __syncthreads();
      const float4* wr = (const float4*)(style_w + t * 512);
      float acc = 0.f;
      for (int k = 0; k < 128; ++k) {
        float4 w4 = wr[k];
        acc += w4.x * sh[k*4] + w4.y * sh[k*4+1] + w4.z * sh[k*4+2] + w4.w * sh[k*4+3];
      }
      mvec[b * 256 + t] = acc + style_b[t] + 1.f;
    }
  } else if (blk < 2240) {
    int idx = (blk - 1088) * 256 + t;
    int co = idx / 1152, r = idx - co * 1152;
    int s = r >> 7, ci = r & 127;
    int ky = s / 3, kx = s - ky * 3;
    w1T[idx] = f2bf(conv1_w[(co * 128 + ci) * 9 + ky * 3 + kx]);
  } else if (blk < 4544) {
    int idx = (blk - 2240) * 256 + t;
    int co = idx / 2304, r = idx - co * 2304;
    int s = r >> 8, ci = r & 255;
    int ky = s / 3, kx = s - ky * 3;
    wmT[idx] = f2bf(mod_w[(co * 256 + ci) * 9 + ky * 3 + kx]);
  } else if (blk < 4800) {
    int o = blk - 4544, i = t;
    const float* p = mod_w + (size_t)(o * 256 + i) * 9;
    float s = 0.f;
#pragma unroll
    for (int k = 0; k < 9; ++k) s += p[k] * p[k];
    SS_T[i * 256 + o] = s;
  } else if (blk < 6360) {
    bool big = blk >= 5320;
    int idx = (big ? (blk - 5320) : (blk - 4800)) * 256 + t;
    const int GR = big ? 32 : 16;
    int g = idx % GR;
    int p = (idx / GR) % 260;
    int b = idx / (GR * 260);
    int y, x2;
    if (p < 66)       { y = 0;       x2 = p; }
    else if (p < 132) { y = 65;      x2 = p - 66; }
    else if (p < 196) { y = p - 131; x2 = 0; }
    else              { y = p - 195; x2 = 65; }
    uint4 z; z.x = 0; z.y = 0; z.z = 0; z.w = 0;
    u16* buf = big ? act2p : act1p;
    int C = big ? 256 : 128;
    *(uint4*)(buf + (((size_t)b * HP + y) * WP + x2) * C + g * 8) = z;
  } else {
    *(float2*)(s2sum + t * 8)     = make_float2(0.f, 0.f);
    *(float2*)(s2sum + t * 8 + 2) = make_float2(0.f, 0.f);
    *(float2*)(s2sum + t * 8 + 4) = make_float2(0.f, 0.f);
    *(float2*)(s2sum + t * 8 + 6) = make_float2(0.f, 0.f);
  }
}

// ---- demod + shortcut-weight scaling fused ----
__global__ __launch_bounds__(256) void demod_sc_kernel(const float* __restrict__ mvec,
                                                       const float* __restrict__ SS_T,
                                                       const float* __restrict__ sc_w,
                                                       float* __restrict__ dvec,
                                                       u16* __restrict__ scTb) {
  __shared__ float m2[256];
  int b = blockIdx.x, t = threadIdx.x;
  float mv = mvec[b * 256 + t];
  m2[t] = mv * mv;
  __syncthreads();
  float acc = 0.f;
  for (int i = 0; i < 256; ++i) acc += m2[i] * SS_T[i * 256 + t];
  float X = acc + 1e-8f;
  dvec[b * 256 + t] = rsqrtf(X);
  float invd = sqrtf(X);
  const float4* wr = (const float4*)(sc_w + t * 128);
  u16* dst = scTb + ((size_t)b * 256 + t) * 128;
#pragma unroll 8
  for (int c4 = 0; c4 < 32; ++c4) {
    float4 w4 = wr[c4];
    u16 o[4] = { f2bf(w4.x * invd), f2bf(w4.y * invd),
                 f2bf(w4.z * invd), f2bf(w4.w * invd) };
    *(uint2*)(dst + c4 * 4) = *(const uint2*)o;
  }
}

// -------- GN1 apply + swish -> act1p; x -> xh. float4 loads, uint4 stores. ----------
__global__ __launch_bounds__(256) void gn1_apply_kernel(const float* __restrict__ x,
                                                        const float2* __restrict__ st1,
                                                        const float* __restrict__ g1,
                                                        const float* __restrict__ b1,
                                                        u16* __restrict__ act1p,
                                                        u16* __restrict__ xh) {
  __shared__ float xs[64][129];
  int blk = blockIdx.x;
  int b = blk >> 6, y = blk & 63;
  int t = threadIdx.x;
#pragma unroll
  for (int pass = 0; pass < 8; ++pass) {
    int c = pass * 16 + (t >> 4);
    int k = t & 15;
    float4 v = *(const float4*)(x + ((size_t)(b * 128 + c)) * 4096 + y * 64 + k * 4);
    xs[k * 4 + 0][c] = v.x;
    xs[k * 4 + 1][c] = v.y;
    xs[k * 4 + 2][c] = v.z;
    xs[k * 4 + 3][c] = v.w;
  }
  __syncthreads();
  const int cg = t & 15, c0 = cg * 8;
  float2 msA = st1[b * 32 + cg * 2];
  float2 msB = st1[b * 32 + cg * 2 + 1];
  float g1r[8], b1r[8];
#pragma unroll
  for (int e = 0; e < 8; ++e) { g1r[e] = g1[c0 + e]; b1r[e] = b1[c0 + e]; }
#pragma unroll
  for (int p = 0; p < 4; ++p) {
    int xi = p * 16 + (t >> 4);
    u16 outA[8], outX[8];
#pragma unroll
    for (int e = 0; e < 8; ++e) {
      float v = xs[xi][c0 + e];
      float2 ms = (e < 4) ? msA : msB;
      float vn = (v - ms.x) * ms.y * g1r[e] + b1r[e];
      float sw = vn / (1.f + __expf(-vn));
      outA[e] = f2bf(sw);
      outX[e] = f2bf(v);
    }
    *(uint4*)(act1p + (((size_t)b * HP + (y + 1)) * WP + (xi + 1)) * 128 + c0) =
        *(const uint4*)outA;
    *(uint4*)(xh + (((size_t)b * 64 + y) * 64 + xi) * 128 + c0) = *(const uint4*)outX;
  }
}

// -- GN2 apply (stats inline from totals) + swish + in-channel mod: h1 -> act2p ------
__global__ __launch_bounds__(256) void gn2_apply_kernel(const u16* __restrict__ h1,
                                                        const float* __restrict__ st2sum,
                                                        const float* __restrict__ g2,
                                                        const float* __restrict__ b2,
                                                        const float* __restrict__ mvec,
                                                        u16* __restrict__ act2p) {
  int idx = blockIdx.x * 256 + threadIdx.x;  // granule id
  int gpix = idx >> 5;
  int gi = idx & 31;
  int c0 = gi * 8;
  int b = gpix >> 12, y = (gpix >> 6) & 63, x = gpix & 63;
  uint4 raw = *(const uint4*)(h1 + (size_t)gpix * 256 + c0);
  const u16* rs = (const u16*)&raw;
  float s  = st2sum[b * 64 + gi * 2];
  float s2 = st2sum[b * 64 + gi * 2 + 1];
  float mean = s / 32768.f;
  float rstd = rsqrtf(s2 / 32768.f - mean * mean + 1e-5f);
  const float* mv = mvec + b * 256 + c0;
  u16 outp[8];
#pragma unroll
  for (int e = 0; e < 8; ++e) {
    float v  = bf2f(rs[e]);
    float vn = (v - mean) * rstd * g2[c0 + e] + b2[c0 + e];
    float sw = vn / (1.f + __expf(-vn));
    outp[e] = f2bf(sw * mv[e]);
  }
  *(uint4*)(act2p + (((size_t)b * HP + (y + 1)) * WP + (x + 1)) * 256 + c0) = *(const uint4*)outp;
}

// ---------- implicit-GEMM conv: 256x256 tile, 8 waves, BK=64, 4-phase schedule ------
// kin-major staging (round 15, FETCH 216->85MB) + m201-order phases: ds_read frags
// BEFORE the barrier (published >=1 barrier ago), stage+vmcnt(4) before barrier,
// lgkmcnt(0)+MFMA after. 2-phase prefetch lead suffices now that staged loads are
// L2-resident (~200cy). Ledger re-audited: each half lands >=1 barrier before its
// pre-barrier read; restage targets last read >=2 barriers prior.
template <int MODE>
__global__ __launch_bounds__(512, 2) void igemm_kernel(const u16* __restrict__ act,
                                                       const u16* __restrict__ wT,
                                                       const float* __restrict__ epi,
                                                       const u16* __restrict__ xh,
                                                       const u16* __restrict__ scTb,
                                                       const float* __restrict__ sc_b,
                                                       u16* __restrict__ h1out,
                                                       float* __restrict__ fout,
                                                       float* __restrict__ st2sum) {
  constexpr int CIN    = (MODE == 0) ? 128 : 256;
  constexpr int KW     = CIN * 9;
  constexpr int NKMAIN = KW / 64;                 // 18 / 36
  constexpr int NKT    = (MODE == 2) ? NKMAIN + 2 : NKMAIN;

  __shared__ __align__(16) unsigned char lds[131072];
  const int tid  = threadIdx.x;
  const int wave = tid >> 6, lane = tid & 63;
  const int wm = wave >> 2, wn = wave & 3;        // 2 x 4 waves
  const int m_base = blockIdx.x * 256;
  const int bimg = m_base >> 12;
  const int ln = lane & 15, l4 = lane >> 4;

  const int srow = lane >> 3;                     // 0..7
  const int glog = (lane & 7) ^ srow;             // pre-swizzled source granule

  u32 pixA[2][2], pixX[2][2], rowB[2][2], rowS[2][2];
#pragma unroll
  for (int j = 0; j < 2; ++j)
#pragma unroll
    for (int h = 0; h < 2; ++h) {
      int mlocal = (wave & 3) * 16 + j * 8 + srow + h * 64 + (wave >> 2) * 128;
      int m = m_base + mlocal;
      int y = (m >> 6) & 63, x = m & 63;
      pixA[j][h] = (u32)((bimg * HP + y) * WP + x) * CIN + glog * 8;
      if (MODE == 2) pixX[j][h] = (u32)m * 128 + glog * 8;
      int co = (wave >> 1) * 64 + h * 32 + (wave & 1) * 16 + j * 8 + srow;
      rowB[j][h] = (u32)co * KW + glog * 8;
      if (MODE == 2) rowS[j][h] = (u32)(bimg * 256 + co) * 128 + glog * 8;
    }

  f32x4 acc[8][4];
#pragma unroll
  for (int i = 0; i < 8; ++i)
#pragma unroll
    for (int j = 0; j < 4; ++j) acc[i][j] = (f32x4){0.f, 0.f, 0.f, 0.f};

  // kin-major / tap-minor decomposition of kt
  auto stageA = [&](int kt, int h, int buf) {
    unsigned char* dst = lds + buf * 65536 + h * 16384 + wave * 2048;
    if (MODE == 2 && kt >= NKMAIN) {
      u32 ko = (u32)(kt - NKMAIN) * 64;
      gload_lds16(xh + pixX[0][h] + ko, dst);
      gload_lds16(xh + pixX[1][h] + ko, dst + 1024);
    } else {
      int q = kt / 9;
      int tap = kt - q * 9;
      int kin = q * 64;
      int ky = tap / 3, kx = tap - ky * 3;
      u32 ko = (u32)((ky * WP + kx) * CIN + kin);
      gload_lds16(act + pixA[0][h] + ko, dst);
      gload_lds16(act + pixA[1][h] + ko, dst + 1024);
    }
  };
  auto stageB = [&](int kt, int g, int buf) {
    unsigned char* dst = lds + buf * 65536 + 32768 + g * 16384 + wave * 2048;
    if (MODE == 2 && kt >= NKMAIN) {
      u32 ko = (u32)(kt - NKMAIN) * 64;
      gload_lds16(scTb + rowS[0][g] + ko, dst);
      gload_lds16(scTb + rowS[1][g] + ko, dst + 1024);
    } else {
      int q = kt / 9;
      int tap = kt - q * 9;
      u32 ko = (u32)(tap * CIN + q * 64);
      gload_lds16(wT + rowB[0][g] + ko, dst);
      gload_lds16(wT + rowB[1][g] + ko, dst + 1024);
    }
  };

  bf16x8 af[8], bf[4];
  auto ldA = [&](int h, int buf) {
    const unsigned char* As = lds + buf * 65536;
#pragma unroll
    for (int f = 0; f < 4; ++f)
#pragma unroll
      for (int kk = 0; kk < 2; ++kk) {
        int lr = h * 128 + wm * 64 + f * 16 + ln;
        int gr = (kk * 4 + l4) ^ (lr & 7);
        af[f * 2 + kk] = *(const bf16x8*)(As + lr * 128 + gr * 16);
      }
  };
  auto ldB = [&](int g, int buf) {
    const unsigned char* Bs = lds + buf * 65536 + 32768;
#pragma unroll
    for (int f1 = 0; f1 < 2; ++f1)
#pragma unroll
      for (int kk = 0; kk < 2; ++kk) {
        int lr = g * 128 + wn * 32 + f1 * 16 + ln;
        int gr = (kk * 4 + l4) ^ (lr & 7);
        bf[f1 * 2 + kk] = *(const bf16x8*)(Bs + lr * 128 + gr * 16);
      }
  };
  auto mmac = [&](int h, int g) {
    __builtin_amdgcn_s_setprio(1);
#pragma unroll
    for (int f = 0; f < 4; ++f)
#pragma unroll
      for (int f1 = 0; f1 < 2; ++f1)
#pragma unroll
        for (int kk = 0; kk < 2; ++kk)
          acc[h * 4 + f][g * 2 + f1] = __builtin_amdgcn_mfma_f32_16x16x32_bf16(
              af[f * 2 + kk], bf[f1 * 2 + kk], acc[h * 4 + f][g * 2 + f1], 0, 0, 0);
    __builtin_amdgcn_s_setprio(0);
  };

#define SB() __builtin_amdgcn_sched_barrier(0)
#define LGKM0() asm volatile("s_waitcnt lgkmcnt(0)" ::: "memory")

  // prologue: stage tile 0 in consumption order; publish Ah0,Bg0
  stageA(0, 0, 0); stageB(0, 0, 0); stageB(0, 1, 0); stageA(0, 1, 0);
  asm volatile("s_waitcnt vmcnt(4)" ::: "memory");
  __builtin_amdgcn_s_barrier();

#pragma unroll 2
  for (int kt = 0; kt < NKT; ++kt) {
    const int cur = kt & 1, nxt = cur ^ 1;
    const bool more = (kt + 1 < NKT);
    // ---- ph0: (h0,g0); stage Ah0(kt+1) ----
    ldB(0, cur); ldA(0, cur); SB();
    if (more) { stageA(kt + 1, 0, nxt);
                asm volatile("s_waitcnt vmcnt(4)" ::: "memory"); }
    else      { asm volatile("s_waitcnt vmcnt(2)" ::: "memory"); }
    __builtin_amdgcn_s_barrier();
    LGKM0(); SB();
    mmac(0, 0);
    // ---- ph1: (h0,g1); stage Bg0(kt+1) ----
    ldB(1, cur); SB();
    if (more) { stageB(kt + 1, 0, nxt);
                asm volatile("s_waitcnt vmcnt(4)" ::: "memory"); }
    else      { asm volatile("s_waitcnt vmcnt(0)" ::: "memory"); }
    __builtin_amdgcn_s_barrier();
    LGKM0(); SB();
    mmac(0, 1);
    // ---- ph2: (h1,g1); stage Bg1(kt+1) ----
    ldA(1, cur); SB();
    if (more) stageB(kt + 1, 1, nxt);
    __builtin_amdgcn_s_barrier();
    LGKM0(); SB();
    mmac(1, 1);
    // ---- ph3: (h1,g0) re-read Bg0; stage Ah1(kt+1) ----
    ldB(0, cur); SB();
    if (more) { stageA(kt + 1, 1, nxt);
                asm volatile("s_waitcnt vmcnt(4)" ::: "memory"); }
    __builtin_amdgcn_s_barrier();
    LGKM0(); SB();
    mmac(1, 0);
  }
#undef SB
#undef LGKM0

  if (MODE == 0) {
    const float* tbrow = epi + bimg * 256;
    float ps[4], ps2[4];
#pragma unroll
    for (int fn = 0; fn < 4; ++fn) { ps[fn] = 0.f; ps2[fn] = 0.f; }
#pragma unroll
    for (int fm = 0; fm < 8; ++fm)
#pragma unroll
      for (int fn = 0; fn < 4; ++fn) {
        int co = wn * 64 + fn * 16 + ln;
        float add = tbrow[co];
#pragma unroll
        for (int i = 0; i < 4; ++i) {
          int m = m_base + wm * 128 + fm * 16 + (l4 << 2) + i;
          float v = acc[fm][fn][i] + add;
          h1out[(size_t)m * 256 + co] = f2bf(v);
          ps[fn] += v; ps2[fn] += v * v;
        }
      }
#pragma unroll
    for (int fn = 0; fn < 4; ++fn) {
      float s = ps[fn], s2 = ps2[fn];
      s += __shfl_xor(s, 1);  s2 += __shfl_xor(s2, 1);
      s += __shfl_xor(s, 2);  s2 += __shfl_xor(s2, 2);
      s += __shfl_xor(s, 4);  s2 += __shfl_xor(s2, 4);
      s += __shfl_xor(s, 16); s2 += __shfl_xor(s2, 16);
      s += __shfl_xor(s, 32); s2 += __shfl_xor(s2, 32);
      if ((lane & 55) == 0) {                 // lanes 0 and 8
        int g = wn * 8 + fn * 2 + (ln >> 3);
        atomicAdd(&st2sum[bimg * 64 + g * 2 + 0], s);
        atomicAdd(&st2sum[bimg * 64 + g * 2 + 1], s2);
      }
    }
  } else {
    float* tile = (float*)lds;              // [64][257] f32
    const int pixb = m_base & 4095;
#pragma unroll
    for (int c = 0; c < 4; ++c) {
      __syncthreads();
      if (wn == c) {
#pragma unroll
        for (int fn = 0; fn < 4; ++fn) {
          int nl = fn * 16 + ln;
          int co = c * 64 + nl;
          float dsc = epi[bimg * 256 + co];
          float scb = sc_b[co];
#pragma unroll
          for (int fm = 0; fm < 8; ++fm)
#pragma unroll
            for (int i = 0; i < 4; ++i) {
              int ml = wm * 128 + fm * 16 + (l4 << 2) + i;
              tile[nl * 257 + ml] = acc[fm][fn][i] * dsc + scb;
            }
        }
      }
      __syncthreads();
#pragma unroll 4
      for (int it = 0; it < 32; ++it) {
        int lin = it * 512 + tid;
        int co_l = lin >> 8, ml = lin & 255;
        fout[((size_t)(bimg * 256 + c * 64 + co_l)) * 4096 + pixb + ml] =
            tile[co_l * 257 + ml];
      }
    }
  }
}

// ------------------------------- launch -------------------------------
extern "C" void kernel_launch(void* const* d_in, const int* in_sizes, int n_in,
                              void* d_out, int out_size, void* d_ws, size_t ws_size,
                              hipStream_t stream) {
  const float* x       = (const float*)d_in[0];
  const float* temb    = (const float*)d_in[1];
  const float* style   = (const float*)d_in[2];
  const float* gn1_g   = (const float*)d_in[3];
  const float* gn1_b   = (const float*)d_in[4];
  const float* conv1_w = (const float*)d_in[5];
  const float* conv1_b = (const float*)d_in[6];
  const float* temb_w  = (const float*)d_in[7];
  const float* temb_b  = (const float*)d_in[8];
  const float* gn2_g   = (const float*)d_in[9];
  const float* gn2_b   = (const float*)d_in[10];
  const float* style_w = (const float*)d_in[11];
  const float* style_b = (const float*)d_in[12];
  const float* mod_w   = (const float*)d_in[13];
  const float* sc_w    = (const float*)d_in[14];
  const float* sc_b    = (const float*)d_in[15];
  float* out = (float*)d_out;
  char* ws = (char*)d_ws;

  size_t o = 0;
  auto alloc = [&](size_t bytes) { size_t r = o; o += (bytes + 255) & ~(size_t)255; return r; };
  const size_t act1p_bytes = (size_t)32 * HP * WP * 128 * 2;
  const size_t xh_bytes    = (size_t)32 * 64 * 64 * 128 * 2;
  const size_t h1_bytes    = (size_t)32 * 4096 * 256 * 2;
  const size_t act2p_bytes = (size_t)32 * HP * WP * 256 * 2;
  size_t o_act1p = alloc(act1p_bytes);
  size_t o_xh    = alloc(xh_bytes);
  size_t o_h1    = alloc(h1_bytes);
  size_t o_act2p = alloc(act2p_bytes);
  size_t o_w1T   = alloc((size_t)256 * 1152 * 2);
  size_t o_wmT   = alloc((size_t)256 * 2304 * 2);
  size_t o_scTb  = alloc((size_t)32 * 256 * 128 * 2);
  size_t o_tb2   = alloc(8192 * 4);
  size_t o_mvec  = alloc(8192 * 4);
  size_t o_dvec  = alloc(8192 * 4);
  size_t o_SS    = alloc((size_t)256 * 256 * 4);
  size_t o_st1   = alloc(1024 * 8);
  size_t o_s2sum = alloc(32 * 32 * 2 * 4);
  if (ws_size < o) return;

  u16*    act1p = (u16*)(ws + o_act1p);
  u16*    xh    = (u16*)(ws + o_xh);
  u16*    h1    = (u16*)(ws + o_h1);
  u16*    act2p = (u16*)(ws + o_act2p);
  u16*    w1T   = (u16*)(ws + o_w1T);
  u16*    wmT   = (u16*)(ws + o_wmT);
  u16*    scTb  = (u16*)(ws + o_scTb);
  float*  tb2   = (float*)(ws + o_tb2);
  float*  mvec  = (float*)(ws + o_mvec);
  float*  dvec  = (float*)(ws + o_dvec);
  float*  SS_T  = (float*)(ws + o_SS);
  float2* st1   = (float2*)(ws + o_st1);
  float*  s2sum = (float*)(ws + o_s2sum);

  prep_kernel<<<6361, 256, 0, stream>>>(x, temb, temb_w, temb_b, conv1_b,
                                        style, style_w, style_b, conv1_w, mod_w,
                                        st1, tb2, mvec, w1T, wmT, SS_T,
                                        act1p, act2p, s2sum);
  gn1_apply_kernel<<<2048, 256, 0, stream>>>(x, st1, gn1_g, gn1_b, act1p, xh);
  demod_sc_kernel<<<32, 256, 0, stream>>>(mvec, SS_T, sc_w, dvec, scTb);

  igemm_kernel<0><<<512, 512, 0, stream>>>(act1p, w1T, tb2, nullptr, nullptr,
                                           nullptr, h1, nullptr, s2sum);

  gn2_apply_kernel<<<16384, 256, 0, stream>>>(h1, s2sum, gn2_g, gn2_b, mvec, act2p);

  igemm_kernel<2><<<512, 512, 0, stream>>>(act2p, wmT, dvec, xh, scTb,
                                           sc_b, nullptr, out, nullptr);
}

// Round 17
// 335.093 us; speedup vs baseline: 1.8126x; 1.8126x over previous
//
#include <hip/hip_runtime.h>
#include <cstdint>

typedef unsigned short u16;
typedef unsigned int   u32;

typedef __attribute__((ext_vector_type(8))) short bf16x8;
typedef __attribute__((ext_vector_type(4))) float f32x4;

#define DEV __device__ __forceinline__

static constexpr int HP = 66, WP = 66;   // padded spatial

DEV u16 f2bf(float f) {
  u32 u = __float_as_uint(f);
  u32 r = (u + 0x7fffu + ((u >> 16) & 1u)) >> 16;
  return (u16)r;
}
DEV float bf2f(u16 v) { return __uint_as_float((u32)v << 16); }

DEV void gload_lds16(const void* g, void* s) {
  __builtin_amdgcn_global_load_lds(
      (const __attribute__((address_space(1))) void*)g,
      (__attribute__((address_space(3))) void*)s, 16, 0, 0);
}

// ---- prep mega-kernel, segments by blockIdx.x:
//  [0,1024)      gn1 stats (b,g)=blk  : st1
//  [1024,1088)   temb proj / style mvec
//  [1088,2240)   w1T repack
//  [2240,4544)   wmT repack
//  [4544,4800)   SS_T[i][o] = sum_k mod_w[o][i][k]^2
//  [4800,5320)   act1p halo zero (C=128)
//  [5320,6360)   act2p halo zero (C=256)
//  [6360]        s2sum zero
__global__ __launch_bounds__(256) void prep_kernel(const float* __restrict__ x,
                                                   const float* __restrict__ temb,
                                                   const float* __restrict__ temb_w,
                                                   const float* __restrict__ temb_b,
                                                   const float* __restrict__ conv1_b,
                                                   const float* __restrict__ style,
                                                   const float* __restrict__ style_w,
                                                   const float* __restrict__ style_b,
                                                   const float* __restrict__ conv1_w,
                                                   const float* __restrict__ mod_w,
                                                   float2* __restrict__ st1,
                                                   float* __restrict__ tb2,
                                                   float* __restrict__ mvec,
                                                   u16* __restrict__ w1T,
                                                   u16* __restrict__ wmT,
                                                   float* __restrict__ SS_T,
                                                   u16* __restrict__ act1p,
                                                   u16* __restrict__ act2p,
                                                   float* __restrict__ s2sum) {
  __shared__ float sh[512];
  int blk = blockIdx.x, t = threadIdx.x;
  if (blk < 1024) {
    const float4* p = (const float4*)(x + (size_t)blk * 16384);
    float s = 0.f, s2 = 0.f;
    for (int i = t; i < 4096; i += 256) {
      float4 v = p[i];
      s  += v.x + v.y + v.z + v.w;
      s2 += v.x*v.x + v.y*v.y + v.z*v.z + v.w*v.w;
    }
    for (int d = 32; d; d >>= 1) { s += __shfl_down(s, d); s2 += __shfl_down(s2, d); }
    if ((t & 63) == 0) { sh[t >> 6] = s; sh[4 + (t >> 6)] = s2; }
    __syncthreads();
    if (t == 0) {
      s  = sh[0] + sh[1] + sh[2] + sh[3];
      s2 = sh[4] + sh[5] + sh[6] + sh[7];
      float mean = s / 16384.f;
      float var  = s2 / 16384.f - mean * mean;
      st1[blk] = make_float2(mean, rsqrtf(var + 1e-5f));
    }
  } else if (blk < 1088) {
    int b2 = blk - 1024;
    if (b2 < 32) {
      int b = b2;
      for (int k = t; k < 512; k += 256) {
        float v = temb[b * 512 + k];
        sh[k] = v / (1.f + __expf(-v));
      }
      __syncthreads();
      const float4* wr = (const float4*)(temb_w + t * 512);
      float acc = 0.f;
      for (int k = 0; k < 128; ++k) {
        float4 w4 = wr[k];
        acc += w4.x * sh[k*4] + w4.y * sh[k*4+1] + w4.z * sh[k*4+2] + w4.w * sh[k*4+3];
      }
      tb2[b * 256 + t] = acc + temb_b[t] + conv1_b[t];
    } else {
      int b = b2 - 32;
      for (int k = t; k < 512; k += 256) sh[k] = style[b * 512 + k];
      __syncthreads();
      const float4* wr = (const float4*)(style_w + t * 512);
      float acc = 0.f;
      for (int k = 0; k < 128; ++k) {
        float4 w4 = wr[k];
        acc += w4.x * sh[k*4] + w4.y * sh[k*4+1] + w4.z * sh[k*4+2] + w4.w * sh[k*4+3];
      }
      mvec[b * 256 + t] = acc + style_b[t] + 1.f;
    }
  } else if (blk < 2240) {
    int idx = (blk - 1088) * 256 + t;
    int co = idx / 1152, r = idx - co * 1152;
    int s = r >> 7, ci = r & 127;
    int ky = s / 3, kx = s - ky * 3;
    w1T[idx] = f2bf(conv1_w[(co * 128 + ci) * 9 + ky * 3 + kx]);
  } else if (blk < 4544) {
    int idx = (blk - 2240) * 256 + t;
    int co = idx / 2304, r = idx - co * 2304;
    int s = r >> 8, ci = r & 255;
    int ky = s / 3, kx = s - ky * 3;
    wmT[idx] = f2bf(mod_w[(co * 256 + ci) * 9 + ky * 3 + kx]);
  } else if (blk < 4800) {
    int o = blk - 4544, i = t;
    const float* p = mod_w + (size_t)(o * 256 + i) * 9;
    float s = 0.f;
#pragma unroll
    for (int k = 0; k < 9; ++k) s += p[k] * p[k];
    SS_T[i * 256 + o] = s;
  } else if (blk < 6360) {
    bool big = blk >= 5320;
    int idx = (big ? (blk - 5320) : (blk - 4800)) * 256 + t;
    const int GR = big ? 32 : 16;
    int g = idx % GR;
    int p = (idx / GR) % 260;
    int b = idx / (GR * 260);
    int y, x2;
    if (p < 66)       { y = 0;       x2 = p; }
    else if (p < 132) { y = 65;      x2 = p - 66; }
    else if (p < 196) { y = p - 131; x2 = 0; }
    else              { y = p - 195; x2 = 65; }
    uint4 z; z.x = 0; z.y = 0; z.z = 0; z.w = 0;
    u16* buf = big ? act2p : act1p;
    int C = big ? 256 : 128;
    *(uint4*)(buf + (((size_t)b * HP + y) * WP + x2) * C + g * 8) = z;
  } else {
    *(float2*)(s2sum + t * 8)     = make_float2(0.f, 0.f);
    *(float2*)(s2sum + t * 8 + 2) = make_float2(0.f, 0.f);
    *(float2*)(s2sum + t * 8 + 4) = make_float2(0.f, 0.f);
    *(float2*)(s2sum + t * 8 + 6) = make_float2(0.f, 0.f);
  }
}

// ---- demod + shortcut-weight scaling fused: per b, thread t = co -------------------
__global__ __launch_bounds__(256) void demod_sc_kernel(const float* __restrict__ mvec,
                                                       const float* __restrict__ SS_T,
                                                       const float* __restrict__ sc_w,
                                                       float* __restrict__ dvec,
                                                       u16* __restrict__ scTb) {
  __shared__ float m2[256];
  int b = blockIdx.x, t = threadIdx.x;
  float mv = mvec[b * 256 + t];
  m2[t] = mv * mv;
  __syncthreads();
  float acc = 0.f;
  for (int i = 0; i < 256; ++i) acc += m2[i] * SS_T[i * 256 + t];
  float X = acc + 1e-8f;
  dvec[b * 256 + t] = rsqrtf(X);
  float invd = sqrtf(X);                      // = 1/dvec
  const float4* wr = (const float4*)(sc_w + t * 128);
  u16* dst = scTb + ((size_t)b * 256 + t) * 128;
#pragma unroll 8
  for (int c4 = 0; c4 < 32; ++c4) {
    float4 w4 = wr[c4];
    u16 o[4] = { f2bf(w4.x * invd), f2bf(w4.y * invd),
                 f2bf(w4.z * invd), f2bf(w4.w * invd) };
    *(uint2*)(dst + c4 * 4) = *(const uint2*)o;
  }
}

// -------- GN1 apply + swish -> act1p; x -> xh. float4 loads, uint4 stores. ----------
__global__ __launch_bounds__(256) void gn1_apply_kernel(const float* __restrict__ x,
                                                        const float2* __restrict__ st1,
                                                        const float* __restrict__ g1,
                                                        const float* __restrict__ b1,
                                                        u16* __restrict__ act1p,
                                                        u16* __restrict__ xh) {
  __shared__ float xs[64][129];
  int blk = blockIdx.x;
  int b = blk >> 6, y = blk & 63;
  int t = threadIdx.x;
#pragma unroll
  for (int pass = 0; pass < 8; ++pass) {
    int c = pass * 16 + (t >> 4);
    int k = t & 15;
    float4 v = *(const float4*)(x + ((size_t)(b * 128 + c)) * 4096 + y * 64 + k * 4);
    xs[k * 4 + 0][c] = v.x;
    xs[k * 4 + 1][c] = v.y;
    xs[k * 4 + 2][c] = v.z;
    xs[k * 4 + 3][c] = v.w;
  }
  __syncthreads();
  const int cg = t & 15, c0 = cg * 8;
  float2 msA = st1[b * 32 + cg * 2];
  float2 msB = st1[b * 32 + cg * 2 + 1];
  float g1r[8], b1r[8];
#pragma unroll
  for (int e = 0; e < 8; ++e) { g1r[e] = g1[c0 + e]; b1r[e] = b1[c0 + e]; }
#pragma unroll
  for (int p = 0; p < 4; ++p) {
    int xi = p * 16 + (t >> 4);
    u16 outA[8], outX[8];
#pragma unroll
    for (int e = 0; e < 8; ++e) {
      float v = xs[xi][c0 + e];
      float2 ms = (e < 4) ? msA : msB;
      float vn = (v - ms.x) * ms.y * g1r[e] + b1r[e];
      float sw = vn / (1.f + __expf(-vn));
      outA[e] = f2bf(sw);
      outX[e] = f2bf(v);
    }
    *(uint4*)(act1p + (((size_t)b * HP + (y + 1)) * WP + (xi + 1)) * 128 + c0) =
        *(const uint4*)outA;
    *(uint4*)(xh + (((size_t)b * 64 + y) * 64 + xi) * 128 + c0) = *(const uint4*)outX;
  }
}

// -- GN2 apply (stats inline from totals) + swish + in-channel mod: h1 -> act2p ------
__global__ __launch_bounds__(256) void gn2_apply_kernel(const u16* __restrict__ h1,
                                                        const float* __restrict__ st2sum,
                                                        const float* __restrict__ g2,
                                                        const float* __restrict__ b2,
                                                        const float* __restrict__ mvec,
                                                        u16* __restrict__ act2p) {
  int idx = blockIdx.x * 256 + threadIdx.x;  // granule id
  int gpix = idx >> 5;
  int gi = idx & 31;
  int c0 = gi * 8;
  int b = gpix >> 12, y = (gpix >> 6) & 63, x = gpix & 63;
  uint4 raw = *(const uint4*)(h1 + (size_t)gpix * 256 + c0);
  const u16* rs = (const u16*)&raw;
  float s  = st2sum[b * 64 + gi * 2];
  float s2 = st2sum[b * 64 + gi * 2 + 1];
  float mean = s / 32768.f;
  float rstd = rsqrtf(s2 / 32768.f - mean * mean + 1e-5f);
  const float* mv = mvec + b * 256 + c0;
  u16 outp[8];
#pragma unroll
  for (int e = 0; e < 8; ++e) {
    float v  = bf2f(rs[e]);
    float vn = (v - mean) * rstd * g2[c0 + e] + b2[c0 + e];
    float sw = vn / (1.f + __expf(-vn));
    outp[e] = f2bf(sw * mv[e]);
  }
  *(uint4*)(act2p + (((size_t)b * HP + (y + 1)) * WP + (x + 1)) * 256 + c0) = *(const uint4*)outp;
}

// ---------- implicit-GEMM conv: 256x256 tile, 8 waves, BK=64, 4-phase schedule ------
// Round-7 proven sync skeleton (stage -> vmcnt(6) -> barrier -> ds_read -> MFMA)
// + kin-major/tap-minor K order (round 15: FETCH 216->85MB, MODE2 155us/46.7%).
template <int MODE>
__global__ __launch_bounds__(512, 2) void igemm_kernel(const u16* __restrict__ act,
                                                       const u16* __restrict__ wT,
                                                       const float* __restrict__ epi,
                                                       const u16* __restrict__ xh,
                                                       const u16* __restrict__ scTb,
                                                       const float* __restrict__ sc_b,
                                                       u16* __restrict__ h1out,
                                                       float* __restrict__ fout,
                                                       float* __restrict__ st2sum) {
  constexpr int CIN    = (MODE == 0) ? 128 : 256;
  constexpr int KW     = CIN * 9;
  constexpr int NKMAIN = KW / 64;                 // 18 / 36
  constexpr int NKT    = (MODE == 2) ? NKMAIN + 2 : NKMAIN;

  __shared__ __align__(16) unsigned char lds[131072];
  const int tid  = threadIdx.x;
  const int wave = tid >> 6, lane = tid & 63;
  const int wm = wave >> 2, wn = wave & 3;        // 2 x 4 waves
  const int m_base = blockIdx.x * 256;
  const int bimg = m_base >> 12;
  const int ln = lane & 15, l4 = lane >> 4;

  // staging lane constants
  const int srow = lane >> 3;                     // 0..7
  const int glog = (lane & 7) ^ srow;             // pre-swizzled source granule

  u32 pixA[2][2], pixX[2][2], rowB[2][2], rowS[2][2];
#pragma unroll
  for (int j = 0; j < 2; ++j)
#pragma unroll
    for (int h = 0; h < 2; ++h) {
      int mlocal = (wave & 3) * 16 + j * 8 + srow + h * 64 + (wave >> 2) * 128;
      int m = m_base + mlocal;
      int y = (m >> 6) & 63, x = m & 63;
      pixA[j][h] = (u32)((bimg * HP + y) * WP + x) * CIN + glog * 8;
      if (MODE == 2) pixX[j][h] = (u32)m * 128 + glog * 8;
      int co = (wave >> 1) * 64 + h * 32 + (wave & 1) * 16 + j * 8 + srow;
      rowB[j][h] = (u32)co * KW + glog * 8;
      if (MODE == 2) rowS[j][h] = (u32)(bimg * 256 + co) * 128 + glog * 8;
    }

  f32x4 acc[8][4];
#pragma unroll
  for (int i = 0; i < 8; ++i)
#pragma unroll
    for (int j = 0; j < 4; ++j) acc[i][j] = (f32x4){0.f, 0.f, 0.f, 0.f};

  // kin-major / tap-minor decomposition of kt
  auto stageA = [&](int kt, int h, int buf) {
    unsigned char* dst = lds + buf * 65536 + h * 16384 + wave * 2048;
    if (MODE == 2 && kt >= NKMAIN) {
      u32 ko = (u32)(kt - NKMAIN) * 64;
      gload_lds16(xh + pixX[0][h] + ko, dst);
      gload_lds16(xh + pixX[1][h] + ko, dst + 1024);
    } else {
      int q = kt / 9;
      int tap = kt - q * 9;
      int kin = q * 64;
      int ky = tap / 3, kx = tap - ky * 3;
      u32 ko = (u32)((ky * WP + kx) * CIN + kin);
      gload_lds16(act + pixA[0][h] + ko, dst);
      gload_lds16(act + pixA[1][h] + ko, dst + 1024);
    }
  };
  auto stageB = [&](int kt, int g, int buf) {
    unsigned char* dst = lds + buf * 65536 + 32768 + g * 16384 + wave * 2048;
    if (MODE == 2 && kt >= NKMAIN) {
      u32 ko = (u32)(kt - NKMAIN) * 64;
      gload_lds16(scTb + rowS[0][g] + ko, dst);
      gload_lds16(scTb + rowS[1][g] + ko, dst + 1024);
    } else {
      int q = kt / 9;
      int tap = kt - q * 9;
      u32 ko = (u32)(tap * CIN + q * 64);
      gload_lds16(wT + rowB[0][g] + ko, dst);
      gload_lds16(wT + rowB[1][g] + ko, dst + 1024);
    }
  };

  bf16x8 af[8], bf[4];
  auto ldA = [&](int h, int buf) {
    const unsigned char* As = lds + buf * 65536;
#pragma unroll
    for (int f = 0; f < 4; ++f)
#pragma unroll
      for (int kk = 0; kk < 2; ++kk) {
        int lr = h * 128 + wm * 64 + f * 16 + ln;
        int gr = (kk * 4 + l4) ^ (lr & 7);
        af[f * 2 + kk] = *(const bf16x8*)(As + lr * 128 + gr * 16);
      }
  };
  auto ldB = [&](int g, int buf) {
    const unsigned char* Bs = lds + buf * 65536 + 32768;
#pragma unroll
    for (int f1 = 0; f1 < 2; ++f1)
#pragma unroll
      for (int kk = 0; kk < 2; ++kk) {
        int lr = g * 128 + wn * 32 + f1 * 16 + ln;
        int gr = (kk * 4 + l4) ^ (lr & 7);
        bf[f1 * 2 + kk] = *(const bf16x8*)(Bs + lr * 128 + gr * 16);
      }
  };
  auto mmac = [&](int h, int g) {
    __builtin_amdgcn_s_setprio(1);
#pragma unroll
    for (int f = 0; f < 4; ++f)
#pragma unroll
      for (int f1 = 0; f1 < 2; ++f1)
#pragma unroll
        for (int kk = 0; kk < 2; ++kk)
          acc[h * 4 + f][g * 2 + f1] = __builtin_amdgcn_mfma_f32_16x16x32_bf16(
              af[f * 2 + kk], bf[f1 * 2 + kk], acc[h * 4 + f][g * 2 + f1], 0, 0, 0);
    __builtin_amdgcn_s_setprio(0);
  };

#define PHASE_BAR() do { __builtin_amdgcn_sched_barrier(0); \
    __builtin_amdgcn_s_barrier(); __builtin_amdgcn_sched_barrier(0); } while (0)

  // prologue: tile 0 -> buf0, in consumption order Ah0, Bg0, Bg1, Ah1
  stageA(0, 0, 0); stageB(0, 0, 0); stageB(0, 1, 0); stageA(0, 1, 0);

#pragma unroll 2
  for (int kt = 0; kt < NKT - 1; ++kt) {
    const int cur = kt & 1, nxt = cur ^ 1;
    // ph0: (h0,g0)
    stageA(kt + 1, 0, nxt);
    asm volatile("s_waitcnt vmcnt(6)" ::: "memory");
    PHASE_BAR();
    ldB(0, cur); ldA(0, cur);
    mmac(0, 0);
    // ph1: (h0,g1)
    stageB(kt + 1, 0, nxt);
    asm volatile("s_waitcnt vmcnt(6)" ::: "memory");
    PHASE_BAR();
    ldB(1, cur);
    mmac(0, 1);
    // ph2: (h1,g1)
    stageB(kt + 1, 1, nxt);
    asm volatile("s_waitcnt vmcnt(6)" ::: "memory");
    PHASE_BAR();
    ldA(1, cur);
    mmac(1, 1);
    // ph3: (h1,g0)
    stageA(kt + 1, 1, nxt);
    PHASE_BAR();
    ldB(0, cur);
    mmac(1, 0);
  }
  {  // last tile (no staging): drain progressively
    const int cur = (NKT - 1) & 1;
    asm volatile("s_waitcnt vmcnt(4)" ::: "memory");
    PHASE_BAR();
    ldB(0, cur); ldA(0, cur); mmac(0, 0);
    asm volatile("s_waitcnt vmcnt(2)" ::: "memory");
    PHASE_BAR();
    ldB(1, cur); mmac(0, 1);
    asm volatile("s_waitcnt vmcnt(0)" ::: "memory");
    PHASE_BAR();
    ldA(1, cur); mmac(1, 1);
    PHASE_BAR();
    ldB(0, cur); mmac(1, 0);
  }
#undef PHASE_BAR

  if (MODE == 0) {
    const float* tbrow = epi + bimg * 256;
    float ps[4], ps2[4];
#pragma unroll
    for (int fn = 0; fn < 4; ++fn) { ps[fn] = 0.f; ps2[fn] = 0.f; }
#pragma unroll
    for (int fm = 0; fm < 8; ++fm)
#pragma unroll
      for (int fn = 0; fn < 4; ++fn) {
        int co = wn * 64 + fn * 16 + ln;
        float add = tbrow[co];
#pragma unroll
        for (int i = 0; i < 4; ++i) {
          int m = m_base + wm * 128 + fm * 16 + (l4 << 2) + i;
          float v = acc[fm][fn][i] + add;
          h1out[(size_t)m * 256 + co] = f2bf(v);
          ps[fn] += v; ps2[fn] += v * v;
        }
      }
    // fused GN2 partial stats (channel-group g = co>>3)
#pragma unroll
    for (int fn = 0; fn < 4; ++fn) {
      float s = ps[fn], s2 = ps2[fn];
      s += __shfl_xor(s, 1);  s2 += __shfl_xor(s2, 1);
      s += __shfl_xor(s, 2);  s2 += __shfl_xor(s2, 2);
      s += __shfl_xor(s, 4);  s2 += __shfl_xor(s2, 4);
      s += __shfl_xor(s, 16); s2 += __shfl_xor(s2, 16);
      s += __shfl_xor(s, 32); s2 += __shfl_xor(s2, 32);
      if ((lane & 55) == 0) {                 // lanes 0 and 8
        int g = wn * 8 + fn * 2 + (ln >> 3);
        atomicAdd(&st2sum[bimg * 64 + g * 2 + 0], s);
        atomicAdd(&st2sum[bimg * 64 + g * 2 + 1], s2);
      }
    }
  } else {
    float* tile = (float*)lds;              // [64][257] f32
    const int pixb = m_base & 4095;
#pragma unroll
    for (int c = 0; c < 4; ++c) {
      __syncthreads();
      if (wn == c) {
#pragma unroll
        for (int fn = 0; fn < 4; ++fn) {
          int nl = fn * 16 + ln;
          int co = c * 64 + nl;
          float dsc = epi[bimg * 256 + co];
          float scb = sc_b[co];
#pragma unroll
          for (int fm = 0; fm < 8; ++fm)
#pragma unroll
            for (int i = 0; i < 4; ++i) {
              int ml = wm * 128 + fm * 16 + (l4 << 2) + i;
              tile[nl * 257 + ml] = acc[fm][fn][i] * dsc + scb;
            }
        }
      }
      __syncthreads();
#pragma unroll 4
      for (int it = 0; it < 32; ++it) {
        int lin = it * 512 + tid;
        int co_l = lin >> 8, ml = lin & 255;
        fout[((size_t)(bimg * 256 + c * 64 + co_l)) * 4096 + pixb + ml] =
            tile[co_l * 257 + ml];
      }
    }
  }
}

// ------------------------------- launch -------------------------------
extern "C" void kernel_launch(void* const* d_in, const int* in_sizes, int n_in,
                              void* d_out, int out_size, void* d_ws, size_t ws_size,
                              hipStream_t stream) {
  const float* x       = (const float*)d_in[0];
  const float* temb    = (const float*)d_in[1];
  const float* style   = (const float*)d_in[2];
  const float* gn1_g   = (const float*)d_in[3];
  const float* gn1_b   = (const float*)d_in[4];
  const float* conv1_w = (const float*)d_in[5];
  const float* conv1_b = (const float*)d_in[6];
  const float* temb_w  = (const float*)d_in[7];
  const float* temb_b  = (const float*)d_in[8];
  const float* gn2_g   = (const float*)d_in[9];
  const float* gn2_b   = (const float*)d_in[10];
  const float* style_w = (const float*)d_in[11];
  const float* style_b = (const float*)d_in[12];
  const float* mod_w   = (const float*)d_in[13];
  const float* sc_w    = (const float*)d_in[14];
  const float* sc_b    = (const float*)d_in[15];
  float* out = (float*)d_out;
  char* ws = (char*)d_ws;

  size_t o = 0;
  auto alloc = [&](size_t bytes) { size_t r = o; o += (bytes + 255) & ~(size_t)255; return r; };
  const size_t act1p_bytes = (size_t)32 * HP * WP * 128 * 2;
  const size_t xh_bytes    = (size_t)32 * 64 * 64 * 128 * 2;
  const size_t h1_bytes    = (size_t)32 * 4096 * 256 * 2;
  const size_t act2p_bytes = (size_t)32 * HP * WP * 256 * 2;
  size_t o_act1p = alloc(act1p_bytes);
  size_t o_xh    = alloc(xh_bytes);
  size_t o_h1    = alloc(h1_bytes);
  size_t o_act2p = alloc(act2p_bytes);
  size_t o_w1T   = alloc((size_t)256 * 1152 * 2);
  size_t o_wmT   = alloc((size_t)256 * 2304 * 2);
  size_t o_scTb  = alloc((size_t)32 * 256 * 128 * 2);
  size_t o_tb2   = alloc(8192 * 4);
  size_t o_mvec  = alloc(8192 * 4);
  size_t o_dvec  = alloc(8192 * 4);
  size_t o_SS    = alloc((size_t)256 * 256 * 4);
  size_t o_st1   = alloc(1024 * 8);
  size_t o_s2sum = alloc(32 * 32 * 2 * 4);
  if (ws_size < o) return;

  u16*    act1p = (u16*)(ws + o_act1p);
  u16*    xh    = (u16*)(ws + o_xh);
  u16*    h1    = (u16*)(ws + o_h1);
  u16*    act2p = (u16*)(ws + o_act2p);
  u16*    w1T   = (u16*)(ws + o_w1T);
  u16*    wmT   = (u16*)(ws + o_wmT);
  u16*    scTb  = (u16*)(ws + o_scTb);
  float*  tb2   = (float*)(ws + o_tb2);
  float*  mvec  = (float*)(ws + o_mvec);
  float*  dvec  = (float*)(ws + o_dvec);
  float*  SS_T  = (float*)(ws + o_SS);
  float2* st1   = (float2*)(ws + o_st1);
  float*  s2sum = (float*)(ws + o_s2sum);

  prep_kernel<<<6361, 256, 0, stream>>>(x, temb, temb_w, temb_b, conv1_b,
                                        style, style_w, style_b, conv1_w, mod_w,
                                        st1, tb2, mvec, w1T, wmT, SS_T,
                                        act1p, act2p, s2sum);
  gn1_apply_kernel<<<2048, 256, 0, stream>>>(x, st1, gn1_g, gn1_b, act1p, xh);
  demod_sc_kernel<<<32, 256, 0, stream>>>(mvec, SS_T, sc_w, dvec, scTb);

  igemm_kernel<0><<<512, 512, 0, stream>>>(act1p, w1T, tb2, nullptr, nullptr,
                                           nullptr, h1, nullptr, s2sum);

  gn2_apply_kernel<<<16384, 256, 0, stream>>>(h1, s2sum, gn2_g, gn2_b, mvec, act2p);

  igemm_kernel<2><<<512, 512, 0, stream>>>(act2p, wmT, dvec, xh, scTb,
                                           sc_b, nullptr, out, nullptr);
}